// Round 5
// baseline (772.198 us; speedup 1.0000x reference)
//
#include <hip/hip_runtime.h>
#include <hip/hip_bf16.h>
#include <math.h>

#define N_EMBD 1024
#define N_HEADC 16
#define HEAD_D 64

typedef __attribute__((ext_vector_type(8))) short short8;
typedef __attribute__((ext_vector_type(4))) float floatx4;

__device__ __forceinline__ ushort f2b(float f) {
    __hip_bfloat16 h = __float2bfloat16(f);
    return *reinterpret_cast<ushort*>(&h);
}

__device__ __forceinline__ void async_cp16(const void* gsrc, void* ldst) {
    __builtin_amdgcn_global_load_lds(
        (const __attribute__((address_space(1))) void*)gsrc,
        (__attribute__((address_space(3))) void*)ldst, 16, 0, 0);
}

// ---- DPP 16-lane butterfly reduction (VALU, no DS-pipe) ----
template <int CTRL>
__device__ __forceinline__ float dpp_f(float v) {
    return __int_as_float(__builtin_amdgcn_update_dpp(
        __float_as_int(v), __float_as_int(v), CTRL, 0xF, 0xF, true));
}
__device__ __forceinline__ float rowmax16(float x) {
    x = fmaxf(x, dpp_f<0xB1>(x));    // quad_perm [1,0,3,2]  (xor 1)
    x = fmaxf(x, dpp_f<0x4E>(x));    // quad_perm [2,3,0,1]  (xor 2)
    x = fmaxf(x, dpp_f<0x141>(x));   // row_half_mirror      (xor ~4)
    x = fmaxf(x, dpp_f<0x140>(x));   // row_mirror           (xor ~8)
    return x;
}
__device__ __forceinline__ float rowsum16(float x) {
    x += dpp_f<0xB1>(x);
    x += dpp_f<0x4E>(x);
    x += dpp_f<0x141>(x);
    x += dpp_f<0x140>(x);
    return x;
}

// XOR-chunk swizzle for 64-elem (128B) LDS rows: 8 chunks of 16B.
// Keeps full-wave ds_read_b128 at structural 8-cycle minimum, no padding.
__device__ __forceinline__ int swz(int row, int e) {
    return (row << 6) + ((((e >> 3) ^ (row & 7)) << 3) | (e & 7));
}

// ---------------------------------------------------------------------------
// LayerNorm: fp32 in, bf16 out. One block (256 thr) per row of C=1024.
// ---------------------------------------------------------------------------
__global__ void ln_kernel(const float* __restrict__ x,
                          const float* __restrict__ w,
                          const float* __restrict__ b,
                          ushort* __restrict__ out, int C) {
    const int row = blockIdx.x;
    const float* xr = x + (size_t)row * C;
    float s = 0.f, ss = 0.f;
    for (int i = threadIdx.x; i < C; i += blockDim.x) {
        float v = xr[i];
        s += v; ss += v * v;
    }
    for (int o = 32; o > 0; o >>= 1) {
        s  += __shfl_down(s, o);
        ss += __shfl_down(ss, o);
    }
    __shared__ float as_[4], ass_[4];
    const int wid = threadIdx.x >> 6, lane = threadIdx.x & 63;
    if (lane == 0) { as_[wid] = s; ass_[wid] = ss; }
    __syncthreads();
    if (threadIdx.x == 0) {
        float ts = 0.f, tss = 0.f;
        for (int i = 0; i < 4; i++) { ts += as_[i]; tss += ass_[i]; }
        as_[0] = ts; ass_[0] = tss;
    }
    __syncthreads();
    const float mu  = as_[0] / C;
    const float var = ass_[0] / C - mu * mu;
    const float inv = rsqrtf(var + 1e-5f);
    ushort* orow = out + (size_t)row * C;
    for (int i = threadIdx.x; i < C; i += blockDim.x) {
        orow[i] = f2b((xr[i] - mu) * inv * w[i] + b[i]);
    }
}

// ---------------------------------------------------------------------------
// Transpose + convert: W[K,N] fp32 -> Wt[N,K] bf16. 32x32 tiles, 256 thr.
// ---------------------------------------------------------------------------
__global__ void convtrans_kernel(const float* __restrict__ W,
                                 ushort* __restrict__ Wt, int K, int N) {
    __shared__ float tile[32][33];
    const int tid = threadIdx.x;
    const int r = tid >> 3;
    const int c4 = (tid & 7) * 4;
    const int bx = blockIdx.x, by = blockIdx.y;

    float4 v = *(const float4*)&W[((size_t)(by * 32 + r)) * N + bx * 32 + c4];
    tile[r][c4 + 0] = v.x; tile[r][c4 + 1] = v.y;
    tile[r][c4 + 2] = v.z; tile[r][c4 + 3] = v.w;
    __syncthreads();

    ushort4 u;
    u.x = f2b(tile[c4 + 0][r]); u.y = f2b(tile[c4 + 1][r]);
    u.z = f2b(tile[c4 + 2][r]); u.w = f2b(tile[c4 + 3][r]);
    *(ushort4*)&Wt[((size_t)(bx * 32 + r)) * K + by * 32 + c4] = u;
}

// ---------------------------------------------------------------------------
// bf16 MFMA GEMM (m97 structure), unchanged from R2.
// ---------------------------------------------------------------------------
__global__ __launch_bounds__(256) void gemm_bf16_kernel(
        const ushort* __restrict__ A,
        const ushort* __restrict__ Bt,
        const float* __restrict__ bias,
        const float* __restrict__ residual,
        float* __restrict__ out32,
        ushort* __restrict__ out16,
        int M, int N, int K, int do_gelu) {
    __shared__ ushort As[128 * 32];
    __shared__ ushort Bs[128 * 32];

    const int tid  = threadIdx.x;
    const int w    = tid >> 6;
    const int lane = tid & 63;
    const int quad = lane >> 4;
    const int l16  = lane & 15;
    const int wm   = w >> 1;
    const int wn   = w & 1;
    const int m0   = blockIdx.y * 128;
    const int n0   = blockIdx.x * 128;

    floatx4 acc[4][4];
#pragma unroll
    for (int i = 0; i < 4; i++)
#pragma unroll
        for (int j = 0; j < 4; j++) acc[i][j] = (floatx4){0.f, 0.f, 0.f, 0.f};

    for (int k0 = 0; k0 < K; k0 += 32) {
#pragma unroll
        for (int l = 0; l < 2; l++) {
            const int cbase = w * 128 + l * 64;
            const int c = cbase + lane;
            const int row = c >> 2, kc8 = (c & 3) * 8;
            async_cp16(A  + (size_t)(m0 + row) * K + k0 + kc8, &As[cbase * 8]);
            async_cp16(Bt + (size_t)(n0 + row) * K + k0 + kc8, &Bs[cbase * 8]);
        }
        __syncthreads();

        short8 a[4], bf[4];
#pragma unroll
        for (int i = 0; i < 4; i++)
            a[i] = *(const short8*)&As[(wm * 64 + i * 16 + l16) * 32 + quad * 8];
#pragma unroll
        for (int j = 0; j < 4; j++)
            bf[j] = *(const short8*)&Bs[(wn * 64 + j * 16 + l16) * 32 + quad * 8];
#pragma unroll
        for (int i = 0; i < 4; i++)
#pragma unroll
            for (int j = 0; j < 4; j++)
                acc[i][j] = __builtin_amdgcn_mfma_f32_16x16x32_bf16(
                    a[i], bf[j], acc[i][j], 0, 0, 0);
        __syncthreads();
    }

#pragma unroll
    for (int i = 0; i < 4; i++) {
#pragma unroll
        for (int j = 0; j < 4; j++) {
            const int nn = n0 + wn * 64 + j * 16 + l16;
            const float bv = bias[nn];
#pragma unroll
            for (int r = 0; r < 4; r++) {
                const int mm = m0 + wm * 64 + i * 16 + quad * 4 + r;
                float v = acc[i][j][r] + bv;
                if (do_gelu) v = 0.5f * v * (1.f + erff(v * 0.70710678118654752f));
                if (residual) v += residual[(size_t)mm * N + nn];
                if (out32) out32[(size_t)mm * N + nn] = v;
                if (out16) out16[(size_t)mm * N + nn] = f2b(v);
            }
        }
    }
}

// ---------------------------------------------------------------------------
// Flash ALiBi attention: triangle-paired q-tiles + split-K (flash-decoding).
// Block (p,h,b*2+s): q-tiles qtA=31-p, qtB=p; kt-range halved by s.
// Partials (m,l,unnormalized O) -> ws; combine kernel merges.
// DPP reductions; XOR-swizzled unpadded LDS (40 KB -> 4 blocks/CU).
// ---------------------------------------------------------------------------
#define LOG2E 1.4426950408889634f

__device__ __forceinline__ void attn_tile_step(
        short8 aq0, short8 aq1,
        const ushort* __restrict__ Ks,
        const ushort* __restrict__ Vt,
        ushort* __restrict__ Ps,
        float* m_r, float* l_r, floatx4* acc,
        int q0, int kt, bool domask,
        float qs2, float slope2, const float* skb,
        int w, int quad, int l16) {
    floatx4 sfrag[4];
#pragma unroll
    for (int kb = 0; kb < 4; kb++) {
        const int kcol = kb * 16 + l16;
        short8 bk0 = *(const short8*)&Ks[swz(kcol, quad * 8)];
        short8 bk1 = *(const short8*)&Ks[swz(kcol, 32 + quad * 8)];
        floatx4 s = (floatx4){0.f, 0.f, 0.f, 0.f};
        s = __builtin_amdgcn_mfma_f32_16x16x32_bf16(aq0, bk0, s, 0, 0, 0);
        s = __builtin_amdgcn_mfma_f32_16x16x32_bf16(aq1, bk1, s, 0, 0, 0);
        sfrag[kb] = s;
    }

    const float ktb = (float)(kt * 64);
#pragma unroll
    for (int r = 0; r < 4; r++) {
        const int q = q0 + w * 16 + quad * 4 + r;
        const float rowc = slope2 * ((float)q - ktb);
        float sv[4];
        float rm = -INFINITY;
#pragma unroll
        for (int kb = 0; kb < 4; kb++) {
            float s = fmaf(sfrag[kb][r], qs2, rowc) - skb[kb];
            if (domask) {
                const int k = kt * 64 + kb * 16 + l16;
                s = (k <= q) ? s : -INFINITY;
            }
            sv[kb] = s;
            rm = fmaxf(rm, s);
        }
        rm = rowmax16(rm);
        const float mnew = fmaxf(m_r[r], rm);
        const float corr = exp2f(m_r[r] - mnew);
        float rs = 0.f;
        const int prow = w * 16 + quad * 4 + r;
#pragma unroll
        for (int kb = 0; kb < 4; kb++) {
            const float pv = exp2f(sv[kb] - mnew);
            rs += pv;
            Ps[swz(prow, kb * 16 + l16)] = f2b(pv);
        }
        rs = rowsum16(rs);
        l_r[r] = l_r[r] * corr + rs;
        m_r[r] = mnew;
#pragma unroll
        for (int db = 0; db < 4; db++) acc[db][r] *= corr;
    }

    short8 ap0 = *(const short8*)&Ps[swz(w * 16 + l16, quad * 8)];
    short8 ap1 = *(const short8*)&Ps[swz(w * 16 + l16, 32 + quad * 8)];
#pragma unroll
    for (int db = 0; db < 4; db++) {
        short8 bv0 = *(const short8*)&Vt[swz(db * 16 + l16, quad * 8)];
        short8 bv1 = *(const short8*)&Vt[swz(db * 16 + l16, 32 + quad * 8)];
        acc[db] = __builtin_amdgcn_mfma_f32_16x16x32_bf16(ap0, bv0, acc[db], 0, 0, 0);
        acc[db] = __builtin_amdgcn_mfma_f32_16x16x32_bf16(ap1, bv1, acc[db], 0, 0, 0);
    }
}

__device__ __forceinline__ void stage_kv(const ushort* __restrict__ qkv_hb,
                                         int kt, int tid,
                                         ushort* __restrict__ Ks,
                                         ushort* __restrict__ Vt) {
#pragma unroll
    for (int i = 0; i < 4; i++) {
        int idx = tid + i * 256;
        int row = idx >> 4, d0 = (idx & 15) * 4;
        const size_t src = (size_t)(kt * 64 + row) * (3 * N_EMBD) + d0;
        *(ushort4*)&Ks[swz(row, d0)] = *(const ushort4*)&qkv_hb[src + N_EMBD];
        ushort4 vv = *(const ushort4*)&qkv_hb[src + 2 * N_EMBD];
        Vt[swz(d0 + 0, row)] = vv.x;
        Vt[swz(d0 + 1, row)] = vv.y;
        Vt[swz(d0 + 2, row)] = vv.z;
        Vt[swz(d0 + 3, row)] = vv.w;
    }
}

__global__ __launch_bounds__(256, 4) void attn_mfma_kernel(
        const ushort* __restrict__ qkv,
        float* __restrict__ accp, float* __restrict__ mlp,
        int B, int T) {
    const int C3 = 3 * N_EMBD;
    const int NT = T / 64;                 // 32
    const int p  = blockIdx.x;             // 0..15
    const int h  = blockIdx.y;
    const int s  = blockIdx.z & 1;         // kt-split
    const int b  = blockIdx.z >> 1;
    const int qtA = NT - 1 - p;
    const int qtB = p;
    const int tid  = threadIdx.x;
    const int lane = tid & 63;
    const int w    = tid >> 6;
    const int quad = lane >> 4;
    const int l16  = lane & 15;

    __shared__ ushort QsA[4096];
    __shared__ ushort QsB[4096];
    __shared__ ushort Ks[4096];
    __shared__ ushort Vt[4096];
    __shared__ ushort Ps[4096];

    const float slope  = exp2f(-0.5f * (float)(h + 1));
    const float slope2 = slope * LOG2E;
    const float qs2    = 0.125f * LOG2E;
    float skb[4];
#pragma unroll
    for (int kb = 0; kb < 4; kb++) skb[kb] = slope2 * (float)(kb * 16 + l16);

    const int q0A = qtA * 64, q0B = qtB * 64;
    const ushort* qkv_hb = qkv + (size_t)b * T * C3 + (size_t)h * HEAD_D;

    // stage both Q tiles (swizzled)
#pragma unroll
    for (int i = 0; i < 4; i++) {
        int idx = tid + i * 256;
        int row = idx >> 4, d0 = (idx & 15) * 4;
        *(ushort4*)&QsA[swz(row, d0)] =
            *(const ushort4*)&qkv_hb[(size_t)(q0A + row) * C3 + d0];
        *(ushort4*)&QsB[swz(row, d0)] =
            *(const ushort4*)&qkv_hb[(size_t)(q0B + row) * C3 + d0];
    }
    __syncthreads();

    const int mrow = w * 16 + l16;
    short8 aqA0 = *(const short8*)&QsA[swz(mrow, quad * 8)];
    short8 aqA1 = *(const short8*)&QsA[swz(mrow, 32 + quad * 8)];
    short8 aqB0 = *(const short8*)&QsB[swz(mrow, quad * 8)];
    short8 aqB1 = *(const short8*)&QsB[swz(mrow, 32 + quad * 8)];

    float mA[4], lA[4], mB[4], lB[4];
    floatx4 accA[4], accB[4];
#pragma unroll
    for (int r = 0; r < 4; r++) {
        mA[r] = -INFINITY; lA[r] = 0.f;
        mB[r] = -INFINITY; lB[r] = 0.f;
        accA[r] = (floatx4){0.f, 0.f, 0.f, 0.f};
        accB[r] = (floatx4){0.f, 0.f, 0.f, 0.f};
    }

    // split ranges: A: [0,nA) halved; B: [0,nB) halved
    const int nA = qtA + 1, nB = qtB + 1;
    const int hAs = (nA + 1) >> 1, hBs = (nB + 1) >> 1;
    const int a_lo = s ? hAs : 0, a_hi = s ? nA : hAs;
    const int b_lo = s ? hBs : 0, b_hi = s ? nB : hBs;

    for (int kt = a_lo; kt < a_hi; kt++) {
        stage_kv(qkv_hb, kt, tid, Ks, Vt);
        __syncthreads();
        attn_tile_step(aqA0, aqA1, Ks, Vt, Ps, mA, lA, accA,
                       q0A, kt, kt == qtA, qs2, slope2, skb, w, quad, l16);
        if (kt >= b_lo && kt < b_hi)
            attn_tile_step(aqB0, aqB1, Ks, Vt, Ps, mB, lB, accB,
                           q0B, kt, kt == qtB, qs2, slope2, skb, w, quad, l16);
        __syncthreads();
    }
    const int b2_hi = min(b_hi, a_lo);
    for (int kt = b_lo; kt < b2_hi; kt++) {
        stage_kv(qkv_hb, kt, tid, Ks, Vt);
        __syncthreads();
        attn_tile_step(aqB0, aqB1, Ks, Vt, Ps, mB, lB, accB,
                       q0B, kt, kt == qtB, qs2, slope2, skb, w, quad, l16);
        __syncthreads();
    }

    // ---- write partials ----
    const size_t slotA = ((size_t)(b * N_HEADC + h) * NT + qtA) * 2 + s;
    const size_t slotB = ((size_t)(b * N_HEADC + h) * NT + qtB) * 2 + s;
#pragma unroll
    for (int r = 0; r < 4; r++) {
        const int row = w * 16 + quad * 4 + r;
#pragma unroll
        for (int db = 0; db < 4; db++) {
            accp[slotA * 4096 + row * 64 + db * 16 + l16] = accA[db][r];
            accp[slotB * 4096 + row * 64 + db * 16 + l16] = accB[db][r];
        }
        if (l16 == 0) {
            *(float2*)&mlp[slotA * 128 + row * 2] = make_float2(mA[r], lA[r]);
            *(float2*)&mlp[slotB * 128 + row * 2] = make_float2(mB[r], lB[r]);
        }
    }
}

// combine the two kt-splits: y = (e0*acc0 + e1*acc1) / (e0*l0 + e1*l1)
__global__ __launch_bounds__(256) void attn_combine_kernel(
        const float* __restrict__ accp, const float* __restrict__ mlp,
        ushort* __restrict__ y, int B, int T) {
    const int NT = T / 64;
    const int qt = blockIdx.x, h = blockIdx.y, b = blockIdx.z;
    const size_t slot = ((size_t)(b * N_HEADC + h) * NT + qt) * 2;
    const int r  = threadIdx.x >> 2;          // q-row 0..63
    const int c0 = (threadIdx.x & 3) * 16;    // d-chunk
    const float m0 = mlp[slot * 128 + r * 2];
    const float l0 = mlp[slot * 128 + r * 2 + 1];
    const float m1 = mlp[(slot + 1) * 128 + r * 2];
    const float l1 = mlp[(slot + 1) * 128 + r * 2 + 1];
    const float M  = fmaxf(m0, m1);
    const float e0 = (l0 > 0.f) ? exp2f(m0 - M) : 0.f;
    const float e1 = (l1 > 0.f) ? exp2f(m1 - M) : 0.f;
    const float inv = 1.f / (l0 * e0 + l1 * e1);
    const float* a0 = accp + slot * 4096 + r * 64 + c0;
    const float* a1 = accp + (slot + 1) * 4096 + r * 64 + c0;
    const int q = qt * 64 + r;
    ushort* yp = y + ((size_t)b * T + q) * N_EMBD + h * HEAD_D + c0;
#pragma unroll
    for (int i = 0; i < 16; i += 4) {
        float4 v0 = *(const float4*)(a0 + i);
        float4 v1 = *(const float4*)(a1 + i);
        yp[i + 0] = f2b((v0.x * e0 + v1.x * e1) * inv);
        yp[i + 1] = f2b((v0.y * e0 + v1.y * e1) * inv);
        yp[i + 2] = f2b((v0.z * e0 + v1.z * e1) * inv);
        yp[i + 3] = f2b((v0.w * e0 + v1.w * e1) * inv);
    }
}

// ---------------------------------------------------------------------------
extern "C" void kernel_launch(void* const* d_in, const int* in_sizes, int n_in,
                              void* d_out, int out_size, void* d_ws, size_t ws_size,
                              hipStream_t stream) {
    const int B = 2, T = 2048, C = N_EMBD;
    const int M = B * T;
    const int NT = T / 64;

    const float* x      = (const float*)d_in[0];
    const float* ln1_w  = (const float*)d_in[1];
    const float* ln1_b  = (const float*)d_in[2];
    const float* w_qkv  = (const float*)d_in[3];
    const float* b_qkv  = (const float*)d_in[4];
    const float* w_proj = (const float*)d_in[5];
    const float* b_proj = (const float*)d_in[6];
    const float* ln2_w  = (const float*)d_in[7];
    const float* ln2_b  = (const float*)d_in[8];
    const float* w_fc   = (const float*)d_in[9];
    const float* b_fc   = (const float*)d_in[10];
    const float* w_fc2  = (const float*)d_in[11];
    const float* b_fc2  = (const float*)d_in[12];
    float* out = (float*)d_out;

    char* ws = (char*)d_ws;
    size_t off = 0;
    ushort* wt_qkv  = (ushort*)(ws + off); off += (size_t)3 * C * C * 2;
    ushort* wt_proj = (ushort*)(ws + off); off += (size_t)C * C * 2;
    ushort* wt_fc   = (ushort*)(ws + off); off += (size_t)4 * C * C * 2;
    ushort* wt_fc2  = (ushort*)(ws + off); off += (size_t)4 * C * C * 2;
    ushort* h16     = (ushort*)(ws + off); off += (size_t)M * C * 2;
    ushort* qkv16   = (ushort*)(ws + off); off += (size_t)M * 3 * C * 2;
    ushort* y16     = (ushort*)(ws + off); off += (size_t)M * C * 2;
    ushort* fc16    = (ushort*)(ws + off); off += (size_t)M * 4 * C * 2;
    float*  accp    = (float*)(ws + off);  off += (size_t)B * N_HEADC * NT * 2 * 64 * 64 * 4;
    float*  mlp     = (float*)(ws + off);  off += (size_t)B * N_HEADC * NT * 2 * 64 * 2 * 4;

    // 0. weight transpose+convert
    convtrans_kernel<<<dim3(3 * C / 32, C / 32), 256, 0, stream>>>(w_qkv, wt_qkv, C, 3 * C);
    convtrans_kernel<<<dim3(C / 32, C / 32), 256, 0, stream>>>(w_proj, wt_proj, C, C);
    convtrans_kernel<<<dim3(4 * C / 32, C / 32), 256, 0, stream>>>(w_fc, wt_fc, C, 4 * C);
    convtrans_kernel<<<dim3(C / 32, 4 * C / 32), 256, 0, stream>>>(w_fc2, wt_fc2, 4 * C, C);

    // 1. h = LN1(x) -> bf16
    ln_kernel<<<M, 256, 0, stream>>>(x, ln1_w, ln1_b, h16, C);

    // 2. qkv = h @ w_qkv + b_qkv -> bf16
    gemm_bf16_kernel<<<dim3(3 * C / 128, M / 128), 256, 0, stream>>>(
        h16, wt_qkv, b_qkv, nullptr, nullptr, qkv16, M, 3 * C, C, 0);

    // 3. flash ALiBi attention, split-K partials + combine -> bf16 y16
    attn_mfma_kernel<<<dim3(NT / 2, N_HEADC, B * 2), 256, 0, stream>>>(
        qkv16, accp, mlp, B, T);
    attn_combine_kernel<<<dim3(NT, N_HEADC, B), 256, 0, stream>>>(
        accp, mlp, y16, B, T);

    // 4. x1 = x + y @ w_proj + b_proj -> d_out (fp32)
    gemm_bf16_kernel<<<dim3(C / 128, M / 128), 256, 0, stream>>>(
        y16, wt_proj, b_proj, x, out, nullptr, M, C, C, 0);

    // 5. h = LN2(x1) -> bf16
    ln_kernel<<<M, 256, 0, stream>>>(out, ln2_w, ln2_b, h16, C);

    // 6. fc = gelu(h @ w_fc + b_fc) -> bf16
    gemm_bf16_kernel<<<dim3(4 * C / 128, M / 128), 256, 0, stream>>>(
        h16, wt_fc, b_fc, nullptr, nullptr, fc16, M, 4 * C, C, 1);

    // 7. out = x1 + fc @ w_fc2 + b_fc2 -> d_out (fp32)
    gemm_bf16_kernel<<<dim3(C / 128, M / 128), 256, 0, stream>>>(
        fc16, wt_fc2, b_fc2, out, out, nullptr, M, C, 4 * C, 0);
}

// Round 6
// 554.490 us; speedup vs baseline: 1.3926x; 1.3926x over previous
//
#include <hip/hip_runtime.h>
#include <hip/hip_bf16.h>
#include <math.h>

#define N_EMBD 1024
#define N_HEADC 16
#define HEAD_D 64

typedef __attribute__((ext_vector_type(8))) short short8;
typedef __attribute__((ext_vector_type(4))) float floatx4;

__device__ __forceinline__ ushort f2b(float f) {
    __hip_bfloat16 h = __float2bfloat16(f);
    return *reinterpret_cast<ushort*>(&h);
}

__device__ __forceinline__ void async_cp16(const void* gsrc, void* ldst) {
    __builtin_amdgcn_global_load_lds(
        (const __attribute__((address_space(1))) void*)gsrc,
        (__attribute__((address_space(3))) void*)ldst, 16, 0, 0);
}

// ---- DPP 16-lane butterfly reduction (VALU, no DS-pipe) ----
template <int CTRL>
__device__ __forceinline__ float dpp_f(float v) {
    return __int_as_float(__builtin_amdgcn_update_dpp(
        __float_as_int(v), __float_as_int(v), CTRL, 0xF, 0xF, true));
}
__device__ __forceinline__ float rowmax16(float x) {
    x = fmaxf(x, dpp_f<0xB1>(x));    // quad_perm xor1
    x = fmaxf(x, dpp_f<0x4E>(x));    // quad_perm xor2
    x = fmaxf(x, dpp_f<0x141>(x));   // row_half_mirror
    x = fmaxf(x, dpp_f<0x140>(x));   // row_mirror
    return x;
}
__device__ __forceinline__ float rowsum16(float x) {
    x += dpp_f<0xB1>(x);
    x += dpp_f<0x4E>(x);
    x += dpp_f<0x141>(x);
    x += dpp_f<0x140>(x);
    return x;
}

// ---------------------------------------------------------------------------
// LayerNorm: fp32 in, bf16 out. One block (256 thr) per row of C=1024.
// ---------------------------------------------------------------------------
__global__ void ln_kernel(const float* __restrict__ x,
                          const float* __restrict__ w,
                          const float* __restrict__ b,
                          ushort* __restrict__ out, int C) {
    const int row = blockIdx.x;
    const float* xr = x + (size_t)row * C;
    float s = 0.f, ss = 0.f;
    for (int i = threadIdx.x; i < C; i += blockDim.x) {
        float v = xr[i];
        s += v; ss += v * v;
    }
    for (int o = 32; o > 0; o >>= 1) {
        s  += __shfl_down(s, o);
        ss += __shfl_down(ss, o);
    }
    __shared__ float as_[4], ass_[4];
    const int wid = threadIdx.x >> 6, lane = threadIdx.x & 63;
    if (lane == 0) { as_[wid] = s; ass_[wid] = ss; }
    __syncthreads();
    if (threadIdx.x == 0) {
        float ts = 0.f, tss = 0.f;
        for (int i = 0; i < 4; i++) { ts += as_[i]; tss += ass_[i]; }
        as_[0] = ts; ass_[0] = tss;
    }
    __syncthreads();
    const float mu  = as_[0] / C;
    const float var = ass_[0] / C - mu * mu;
    const float inv = rsqrtf(var + 1e-5f);
    ushort* orow = out + (size_t)row * C;
    for (int i = threadIdx.x; i < C; i += blockDim.x) {
        orow[i] = f2b((xr[i] - mu) * inv * w[i] + b[i]);
    }
}

// ---------------------------------------------------------------------------
// Transpose + convert: W[K,N] fp32 -> Wt[N,K] bf16. 32x32 tiles, 256 thr.
// ---------------------------------------------------------------------------
__global__ void convtrans_kernel(const float* __restrict__ W,
                                 ushort* __restrict__ Wt, int K, int N) {
    __shared__ float tile[32][33];
    const int tid = threadIdx.x;
    const int r = tid >> 3;
    const int c4 = (tid & 7) * 4;
    const int bx = blockIdx.x, by = blockIdx.y;

    float4 v = *(const float4*)&W[((size_t)(by * 32 + r)) * N + bx * 32 + c4];
    tile[r][c4 + 0] = v.x; tile[r][c4 + 1] = v.y;
    tile[r][c4 + 2] = v.z; tile[r][c4 + 3] = v.w;
    __syncthreads();

    ushort4 u;
    u.x = f2b(tile[c4 + 0][r]); u.y = f2b(tile[c4 + 1][r]);
    u.z = f2b(tile[c4 + 2][r]); u.w = f2b(tile[c4 + 3][r]);
    *(ushort4*)&Wt[((size_t)(bx * 32 + r)) * K + by * 32 + c4] = u;
}

// ---------------------------------------------------------------------------
// bf16 MFMA GEMM (m97 structure), unchanged.
// ---------------------------------------------------------------------------
__global__ __launch_bounds__(256) void gemm_bf16_kernel(
        const ushort* __restrict__ A,
        const ushort* __restrict__ Bt,
        const float* __restrict__ bias,
        const float* __restrict__ residual,
        float* __restrict__ out32,
        ushort* __restrict__ out16,
        int M, int N, int K, int do_gelu) {
    __shared__ ushort As[128 * 32];
    __shared__ ushort Bs[128 * 32];

    const int tid  = threadIdx.x;
    const int w    = tid >> 6;
    const int lane = tid & 63;
    const int quad = lane >> 4;
    const int l16  = lane & 15;
    const int wm   = w >> 1;
    const int wn   = w & 1;
    const int m0   = blockIdx.y * 128;
    const int n0   = blockIdx.x * 128;

    floatx4 acc[4][4];
#pragma unroll
    for (int i = 0; i < 4; i++)
#pragma unroll
        for (int j = 0; j < 4; j++) acc[i][j] = (floatx4){0.f, 0.f, 0.f, 0.f};

    for (int k0 = 0; k0 < K; k0 += 32) {
#pragma unroll
        for (int l = 0; l < 2; l++) {
            const int cbase = w * 128 + l * 64;
            const int c = cbase + lane;
            const int row = c >> 2, kc8 = (c & 3) * 8;
            async_cp16(A  + (size_t)(m0 + row) * K + k0 + kc8, &As[cbase * 8]);
            async_cp16(Bt + (size_t)(n0 + row) * K + k0 + kc8, &Bs[cbase * 8]);
        }
        __syncthreads();

        short8 a[4], bf[4];
#pragma unroll
        for (int i = 0; i < 4; i++)
            a[i] = *(const short8*)&As[(wm * 64 + i * 16 + l16) * 32 + quad * 8];
#pragma unroll
        for (int j = 0; j < 4; j++)
            bf[j] = *(const short8*)&Bs[(wn * 64 + j * 16 + l16) * 32 + quad * 8];
#pragma unroll
        for (int i = 0; i < 4; i++)
#pragma unroll
            for (int j = 0; j < 4; j++)
                acc[i][j] = __builtin_amdgcn_mfma_f32_16x16x32_bf16(
                    a[i], bf[j], acc[i][j], 0, 0, 0);
        __syncthreads();
    }

#pragma unroll
    for (int i = 0; i < 4; i++) {
#pragma unroll
        for (int j = 0; j < 4; j++) {
            const int nn = n0 + wn * 64 + j * 16 + l16;
            const float bv = bias[nn];
#pragma unroll
            for (int r = 0; r < 4; r++) {
                const int mm = m0 + wm * 64 + i * 16 + quad * 4 + r;
                float v = acc[i][j][r] + bv;
                if (do_gelu) v = 0.5f * v * (1.f + erff(v * 0.70710678118654752f));
                if (residual) v += residual[(size_t)mm * N + nn];
                if (out32) out32[(size_t)mm * N + nn] = v;
                if (out16) out16[(size_t)mm * N + nn] = f2b(v);
            }
        }
    }
}

// ---------------------------------------------------------------------------
// Flash ALiBi attention: one q-tile per block + split-K x2.
// Grid (NT, H, B*2): 2048 blocks (8/CU oversubscribed; imbalance refills).
// Single-tile state (no spills). Padded LDS (36.9 KB -> 4 blocks/CU).
// Partials (m, l, unnormalized O) -> ws; combine kernel merges.
// ---------------------------------------------------------------------------
#define AT_PAD 72
#define LOG2E 1.4426950408889634f

__global__ __launch_bounds__(256) void attn_mfma_kernel(
        const ushort* __restrict__ qkv,
        float* __restrict__ accp, float* __restrict__ mlp,
        int B, int T) {
    const int C3 = 3 * N_EMBD;
    const int NT = T / 64;                 // 32
    const int qt = blockIdx.x;
    const int h  = blockIdx.y;
    const int s  = blockIdx.z & 1;         // kt-split
    const int b  = blockIdx.z >> 1;
    const int tid  = threadIdx.x;
    const int lane = tid & 63;
    const int w    = tid >> 6;
    const int quad = lane >> 4;
    const int l16  = lane & 15;

    __shared__ ushort Qs[64][AT_PAD];
    __shared__ ushort Ks[64][AT_PAD];
    __shared__ ushort Vt[64][AT_PAD];
    __shared__ ushort Ps[64][AT_PAD];

    const float slope  = exp2f(-0.5f * (float)(h + 1));
    const float slope2 = slope * LOG2E;
    const float qs2    = 0.125f * LOG2E;
    float skb[4];
#pragma unroll
    for (int kb = 0; kb < 4; kb++) skb[kb] = slope2 * (float)(kb * 16 + l16);

    const int q0 = qt * 64;
    const ushort* qkv_hb = qkv + (size_t)b * T * C3 + (size_t)h * HEAD_D;

    // stage Q tile
#pragma unroll
    for (int i = 0; i < 4; i++) {
        int idx = tid + i * 256;
        int row = idx >> 4, d0 = (idx & 15) * 4;
        *(ushort4*)&Qs[row][d0] =
            *(const ushort4*)&qkv_hb[(size_t)(q0 + row) * C3 + d0];
    }
    __syncthreads();

    const int mrow = w * 16 + l16;
    short8 aq0 = *(const short8*)&Qs[mrow][quad * 8];
    short8 aq1 = *(const short8*)&Qs[mrow][32 + quad * 8];

    float m_r[4], l_r[4];
    floatx4 acc[4];
#pragma unroll
    for (int r = 0; r < 4; r++) {
        m_r[r] = -INFINITY; l_r[r] = 0.f;
        acc[r] = (floatx4){0.f, 0.f, 0.f, 0.f};
    }

    // split [0, qt+1) into two halves by s
    const int n  = qt + 1;
    const int hs = (n + 1) >> 1;
    const int lo = s ? hs : 0;
    const int hi = s ? n : hs;

    for (int kt = lo; kt < hi; kt++) {
        // ---- stage K (row-major) and V (transposed) ----
#pragma unroll
        for (int i = 0; i < 4; i++) {
            int idx = tid + i * 256;
            int row = idx >> 4, d0 = (idx & 15) * 4;
            const size_t src = (size_t)(kt * 64 + row) * C3 + d0;
            *(ushort4*)&Ks[row][d0] = *(const ushort4*)&qkv_hb[src + N_EMBD];
            ushort4 vv = *(const ushort4*)&qkv_hb[src + 2 * N_EMBD];
            Vt[d0 + 0][row] = vv.x;
            Vt[d0 + 1][row] = vv.y;
            Vt[d0 + 2][row] = vv.z;
            Vt[d0 + 3][row] = vv.w;
        }
        __syncthreads();

        // ---- scores ----
        floatx4 sfrag[4];
#pragma unroll
        for (int kb = 0; kb < 4; kb++) {
            const int kcol = kb * 16 + l16;
            short8 bk0 = *(const short8*)&Ks[kcol][quad * 8];
            short8 bk1 = *(const short8*)&Ks[kcol][32 + quad * 8];
            floatx4 sc = (floatx4){0.f, 0.f, 0.f, 0.f};
            sc = __builtin_amdgcn_mfma_f32_16x16x32_bf16(aq0, bk0, sc, 0, 0, 0);
            sc = __builtin_amdgcn_mfma_f32_16x16x32_bf16(aq1, bk1, sc, 0, 0, 0);
            sfrag[kb] = sc;
        }

        // ---- ALiBi + (diagonal-only) mask + online softmax ----
        const bool domask = (kt == qt);
        const float ktb = (float)(kt * 64);
#pragma unroll
        for (int r = 0; r < 4; r++) {
            const int q = q0 + w * 16 + quad * 4 + r;
            const float rowc = slope2 * ((float)q - ktb);
            float sv[4];
            float rm = -INFINITY;
#pragma unroll
            for (int kb = 0; kb < 4; kb++) {
                float sc = fmaf(sfrag[kb][r], qs2, rowc) - skb[kb];
                if (domask) {
                    const int k = kt * 64 + kb * 16 + l16;
                    sc = (k <= q) ? sc : -INFINITY;
                }
                sv[kb] = sc;
                rm = fmaxf(rm, sc);
            }
            rm = rowmax16(rm);
            const float mnew = fmaxf(m_r[r], rm);
            const float corr = exp2f(m_r[r] - mnew);
            float rs = 0.f;
            const int prow = w * 16 + quad * 4 + r;
#pragma unroll
            for (int kb = 0; kb < 4; kb++) {
                const float pv = exp2f(sv[kb] - mnew);
                rs += pv;
                Ps[prow][kb * 16 + l16] = f2b(pv);
            }
            rs = rowsum16(rs);
            l_r[r] = l_r[r] * corr + rs;
            m_r[r] = mnew;
#pragma unroll
            for (int db = 0; db < 4; db++) acc[db][r] *= corr;
        }

        // ---- PV (Ps rows wave-private; no barrier before) ----
        short8 ap0 = *(const short8*)&Ps[w * 16 + l16][quad * 8];
        short8 ap1 = *(const short8*)&Ps[w * 16 + l16][32 + quad * 8];
#pragma unroll
        for (int db = 0; db < 4; db++) {
            short8 bv0 = *(const short8*)&Vt[db * 16 + l16][quad * 8];
            short8 bv1 = *(const short8*)&Vt[db * 16 + l16][32 + quad * 8];
            acc[db] = __builtin_amdgcn_mfma_f32_16x16x32_bf16(ap0, bv0, acc[db], 0, 0, 0);
            acc[db] = __builtin_amdgcn_mfma_f32_16x16x32_bf16(ap1, bv1, acc[db], 0, 0, 0);
        }
        __syncthreads();
    }

    // ---- write partials ----
    const size_t slot = ((size_t)(b * N_HEADC + h) * NT + qt) * 2 + s;
#pragma unroll
    for (int r = 0; r < 4; r++) {
        const int row = w * 16 + quad * 4 + r;
#pragma unroll
        for (int db = 0; db < 4; db++)
            accp[slot * 4096 + row * 64 + db * 16 + l16] = acc[db][r];
        if (l16 == 0)
            *(float2*)&mlp[slot * 128 + row * 2] = make_float2(m_r[r], l_r[r]);
    }
}

// combine the two kt-splits: y = (e0*acc0 + e1*acc1) / (e0*l0 + e1*l1)
__global__ __launch_bounds__(256) void attn_combine_kernel(
        const float* __restrict__ accp, const float* __restrict__ mlp,
        ushort* __restrict__ y, int B, int T) {
    const int NT = T / 64;
    const int qt = blockIdx.x, h = blockIdx.y, b = blockIdx.z;
    const size_t slot = ((size_t)(b * N_HEADC + h) * NT + qt) * 2;
    const int r  = threadIdx.x >> 2;          // q-row 0..63
    const int c0 = (threadIdx.x & 3) * 16;    // d-chunk
    const float m0 = mlp[slot * 128 + r * 2];
    const float l0 = mlp[slot * 128 + r * 2 + 1];
    const float m1 = mlp[(slot + 1) * 128 + r * 2];
    const float l1 = mlp[(slot + 1) * 128 + r * 2 + 1];
    const float M  = fmaxf(m0, m1);
    const float e0 = (l0 > 0.f) ? exp2f(m0 - M) : 0.f;
    const float e1 = (l1 > 0.f) ? exp2f(m1 - M) : 0.f;
    const float inv = 1.f / (l0 * e0 + l1 * e1);
    const float* a0 = accp + slot * 4096 + r * 64 + c0;
    const float* a1 = accp + (slot + 1) * 4096 + r * 64 + c0;
    const int q = qt * 64 + r;
    ushort* yp = y + ((size_t)b * T + q) * N_EMBD + h * HEAD_D + c0;
#pragma unroll
    for (int i = 0; i < 16; i += 4) {
        float4 v0 = *(const float4*)(a0 + i);
        float4 v1 = *(const float4*)(a1 + i);
        yp[i + 0] = f2b((v0.x * e0 + v1.x * e1) * inv);
        yp[i + 1] = f2b((v0.y * e0 + v1.y * e1) * inv);
        yp[i + 2] = f2b((v0.z * e0 + v1.z * e1) * inv);
        yp[i + 3] = f2b((v0.w * e0 + v1.w * e1) * inv);
    }
}

// ---------------------------------------------------------------------------
extern "C" void kernel_launch(void* const* d_in, const int* in_sizes, int n_in,
                              void* d_out, int out_size, void* d_ws, size_t ws_size,
                              hipStream_t stream) {
    const int B = 2, T = 2048, C = N_EMBD;
    const int M = B * T;
    const int NT = T / 64;

    const float* x      = (const float*)d_in[0];
    const float* ln1_w  = (const float*)d_in[1];
    const float* ln1_b  = (const float*)d_in[2];
    const float* w_qkv  = (const float*)d_in[3];
    const float* b_qkv  = (const float*)d_in[4];
    const float* w_proj = (const float*)d_in[5];
    const float* b_proj = (const float*)d_in[6];
    const float* ln2_w  = (const float*)d_in[7];
    const float* ln2_b  = (const float*)d_in[8];
    const float* w_fc   = (const float*)d_in[9];
    const float* b_fc   = (const float*)d_in[10];
    const float* w_fc2  = (const float*)d_in[11];
    const float* b_fc2  = (const float*)d_in[12];
    float* out = (float*)d_out;

    char* ws = (char*)d_ws;
    size_t off = 0;
    ushort* wt_qkv  = (ushort*)(ws + off); off += (size_t)3 * C * C * 2;
    ushort* wt_proj = (ushort*)(ws + off); off += (size_t)C * C * 2;
    ushort* wt_fc   = (ushort*)(ws + off); off += (size_t)4 * C * C * 2;
    ushort* wt_fc2  = (ushort*)(ws + off); off += (size_t)4 * C * C * 2;
    ushort* h16     = (ushort*)(ws + off); off += (size_t)M * C * 2;
    ushort* qkv16   = (ushort*)(ws + off); off += (size_t)M * 3 * C * 2;
    ushort* y16     = (ushort*)(ws + off); off += (size_t)M * C * 2;
    ushort* fc16    = (ushort*)(ws + off); off += (size_t)M * 4 * C * 2;
    float*  accp    = (float*)(ws + off);  off += (size_t)B * N_HEADC * NT * 2 * 64 * 64 * 4;
    float*  mlp     = (float*)(ws + off);  off += (size_t)B * N_HEADC * NT * 2 * 64 * 2 * 4;

    // 0. weight transpose+convert
    convtrans_kernel<<<dim3(3 * C / 32, C / 32), 256, 0, stream>>>(w_qkv, wt_qkv, C, 3 * C);
    convtrans_kernel<<<dim3(C / 32, C / 32), 256, 0, stream>>>(w_proj, wt_proj, C, C);
    convtrans_kernel<<<dim3(4 * C / 32, C / 32), 256, 0, stream>>>(w_fc, wt_fc, C, 4 * C);
    convtrans_kernel<<<dim3(C / 32, 4 * C / 32), 256, 0, stream>>>(w_fc2, wt_fc2, 4 * C, C);

    // 1. h = LN1(x) -> bf16
    ln_kernel<<<M, 256, 0, stream>>>(x, ln1_w, ln1_b, h16, C);

    // 2. qkv = h @ w_qkv + b_qkv -> bf16
    gemm_bf16_kernel<<<dim3(3 * C / 128, M / 128), 256, 0, stream>>>(
        h16, wt_qkv, b_qkv, nullptr, nullptr, qkv16, M, 3 * C, C, 0);

    // 3. flash ALiBi attention, split-K partials + combine -> bf16 y16
    attn_mfma_kernel<<<dim3(NT, N_HEADC, B * 2), 256, 0, stream>>>(
        qkv16, accp, mlp, B, T);
    attn_combine_kernel<<<dim3(NT, N_HEADC, B), 256, 0, stream>>>(
        accp, mlp, y16, B, T);

    // 4. x1 = x + y @ w_proj + b_proj -> d_out (fp32)
    gemm_bf16_kernel<<<dim3(C / 128, M / 128), 256, 0, stream>>>(
        y16, wt_proj, b_proj, x, out, nullptr, M, C, C, 0);

    // 5. h = LN2(x1) -> bf16
    ln_kernel<<<M, 256, 0, stream>>>(out, ln2_w, ln2_b, h16, C);

    // 6. fc = gelu(h @ w_fc + b_fc) -> bf16
    gemm_bf16_kernel<<<dim3(4 * C / 128, M / 128), 256, 0, stream>>>(
        h16, wt_fc, b_fc, nullptr, nullptr, fc16, M, 4 * C, C, 1);

    // 7. out = x1 + fc @ w_fc2 + b_fc2 -> d_out (fp32)
    gemm_bf16_kernel<<<dim3(C / 128, M / 128), 256, 0, stream>>>(
        fc16, wt_fc2, b_fc2, out, out, nullptr, M, C, 4 * C, 0);
}

// Round 8
// 526.531 us; speedup vs baseline: 1.4666x; 1.0531x over previous
//
#include <hip/hip_runtime.h>
#include <hip/hip_bf16.h>
#include <math.h>

#define N_EMBD 1024
#define N_HEADC 16
#define HEAD_D 64

typedef __attribute__((ext_vector_type(8))) short short8;
typedef __attribute__((ext_vector_type(4))) float floatx4;

__device__ __forceinline__ ushort f2b(float f) {
    __hip_bfloat16 h = __float2bfloat16(f);
    return *reinterpret_cast<ushort*>(&h);
}

__device__ __forceinline__ void async_cp16(const void* gsrc, void* ldst) {
    __builtin_amdgcn_global_load_lds(
        (const __attribute__((address_space(1))) void*)gsrc,
        (__attribute__((address_space(3))) void*)ldst, 16, 0, 0);
}

// ---- DPP 16-lane butterfly sum (VALU, no DS-pipe) ----
template <int CTRL>
__device__ __forceinline__ float dpp_f(float v) {
    return __int_as_float(__builtin_amdgcn_update_dpp(
        __float_as_int(v), __float_as_int(v), CTRL, 0xF, 0xF, true));
}
__device__ __forceinline__ float rowsum16(float x) {
    x += dpp_f<0xB1>(x);     // quad_perm xor1
    x += dpp_f<0x4E>(x);     // quad_perm xor2
    x += dpp_f<0x141>(x);    // row_half_mirror
    x += dpp_f<0x140>(x);    // row_mirror
    return x;
}

// ---------------------------------------------------------------------------
// LayerNorm: fp32 in, bf16 out. One block (256 thr) per row of C=1024.
// ---------------------------------------------------------------------------
__global__ void ln_kernel(const float* __restrict__ x,
                          const float* __restrict__ w,
                          const float* __restrict__ b,
                          ushort* __restrict__ out, int C) {
    const int row = blockIdx.x;
    const float* xr = x + (size_t)row * C;
    float s = 0.f, ss = 0.f;
    for (int i = threadIdx.x; i < C; i += blockDim.x) {
        float v = xr[i];
        s += v; ss += v * v;
    }
    for (int o = 32; o > 0; o >>= 1) {
        s  += __shfl_down(s, o);
        ss += __shfl_down(ss, o);
    }
    __shared__ float as_[4], ass_[4];
    const int wid = threadIdx.x >> 6, lane = threadIdx.x & 63;
    if (lane == 0) { as_[wid] = s; ass_[wid] = ss; }
    __syncthreads();
    if (threadIdx.x == 0) {
        float ts = 0.f, tss = 0.f;
        for (int i = 0; i < 4; i++) { ts += as_[i]; tss += ass_[i]; }
        as_[0] = ts; ass_[0] = tss;
    }
    __syncthreads();
    const float mu  = as_[0] / C;
    const float var = ass_[0] / C - mu * mu;
    const float inv = rsqrtf(var + 1e-5f);
    ushort* orow = out + (size_t)row * C;
    for (int i = threadIdx.x; i < C; i += blockDim.x) {
        orow[i] = f2b((xr[i] - mu) * inv * w[i] + b[i]);
    }
}

// ---------------------------------------------------------------------------
// Transpose + convert: W[K,N] fp32 -> Wt[N,K] bf16. 32x32 tiles, 256 thr.
// ---------------------------------------------------------------------------
__global__ void convtrans_kernel(const float* __restrict__ W,
                                 ushort* __restrict__ Wt, int K, int N) {
    __shared__ float tile[32][33];
    const int tid = threadIdx.x;
    const int r = tid >> 3;
    const int c4 = (tid & 7) * 4;
    const int bx = blockIdx.x, by = blockIdx.y;

    float4 v = *(const float4*)&W[((size_t)(by * 32 + r)) * N + bx * 32 + c4];
    tile[r][c4 + 0] = v.x; tile[r][c4 + 1] = v.y;
    tile[r][c4 + 2] = v.z; tile[r][c4 + 3] = v.w;
    __syncthreads();

    ushort4 u;
    u.x = f2b(tile[c4 + 0][r]); u.y = f2b(tile[c4 + 1][r]);
    u.z = f2b(tile[c4 + 2][r]); u.w = f2b(tile[c4 + 3][r]);
    *(ushort4*)&Wt[((size_t)(bx * 32 + r)) * K + by * 32 + c4] = u;
}

// ---------------------------------------------------------------------------
// V transpose: qkv16 V-part [b][t][h,d] -> vT [b][h][d][T] (bf16).
// grid (T/64, H, B), 256 thr, 64x64 tiles.
// ---------------------------------------------------------------------------
__global__ void vtrans_kernel(const ushort* __restrict__ qkv,
                              ushort* __restrict__ vT, int B, int T) {
    __shared__ ushort Ts[64][72];
    const int C3 = 3 * N_EMBD;
    const int t0 = blockIdx.x * 64;
    const int h  = blockIdx.y;
    const int b  = blockIdx.z;
    const int tid = threadIdx.x;
    const ushort* src = qkv + (size_t)b * T * C3 + 2 * N_EMBD + h * HEAD_D;
#pragma unroll
    for (int i = 0; i < 4; i++) {
        int idx = tid + i * 256;
        int r = idx >> 4, c4 = (idx & 15) * 4;
        *(ushort4*)&Ts[r][c4] = *(const ushort4*)&src[(size_t)(t0 + r) * C3 + c4];
    }
    __syncthreads();
    ushort* dst = vT + (size_t)(b * N_HEADC + h) * HEAD_D * T;
#pragma unroll
    for (int i = 0; i < 4; i++) {
        int idx = tid + i * 256;
        int d = idx >> 4, t4 = (idx & 15) * 4;
        ushort4 u;
        u.x = Ts[t4 + 0][d]; u.y = Ts[t4 + 1][d];
        u.z = Ts[t4 + 2][d]; u.w = Ts[t4 + 3][d];
        *(ushort4*)&dst[(size_t)d * T + t0 + t4] = u;
    }
}

// ---------------------------------------------------------------------------
// bf16 MFMA GEMM (m97 structure), unchanged.
// ---------------------------------------------------------------------------
__global__ __launch_bounds__(256) void gemm_bf16_kernel(
        const ushort* __restrict__ A,
        const ushort* __restrict__ Bt,
        const float* __restrict__ bias,
        const float* __restrict__ residual,
        float* __restrict__ out32,
        ushort* __restrict__ out16,
        int M, int N, int K, int do_gelu) {
    __shared__ ushort As[128 * 32];
    __shared__ ushort Bs[128 * 32];

    const int tid  = threadIdx.x;
    const int w    = tid >> 6;
    const int lane = tid & 63;
    const int quad = lane >> 4;
    const int l16  = lane & 15;
    const int wm   = w >> 1;
    const int wn   = w & 1;
    const int m0   = blockIdx.y * 128;
    const int n0   = blockIdx.x * 128;

    floatx4 acc[4][4];
#pragma unroll
    for (int i = 0; i < 4; i++)
#pragma unroll
        for (int j = 0; j < 4; j++) acc[i][j] = (floatx4){0.f, 0.f, 0.f, 0.f};

    for (int k0 = 0; k0 < K; k0 += 32) {
#pragma unroll
        for (int l = 0; l < 2; l++) {
            const int cbase = w * 128 + l * 64;
            const int c = cbase + lane;
            const int row = c >> 2, kc8 = (c & 3) * 8;
            async_cp16(A  + (size_t)(m0 + row) * K + k0 + kc8, &As[cbase * 8]);
            async_cp16(Bt + (size_t)(n0 + row) * K + k0 + kc8, &Bs[cbase * 8]);
        }
        __syncthreads();

        short8 a[4], bf[4];
#pragma unroll
        for (int i = 0; i < 4; i++)
            a[i] = *(const short8*)&As[(wm * 64 + i * 16 + l16) * 32 + quad * 8];
#pragma unroll
        for (int j = 0; j < 4; j++)
            bf[j] = *(const short8*)&Bs[(wn * 64 + j * 16 + l16) * 32 + quad * 8];
#pragma unroll
        for (int i = 0; i < 4; i++)
#pragma unroll
            for (int j = 0; j < 4; j++)
                acc[i][j] = __builtin_amdgcn_mfma_f32_16x16x32_bf16(
                    a[i], bf[j], acc[i][j], 0, 0, 0);
        __syncthreads();
    }

#pragma unroll
    for (int i = 0; i < 4; i++) {
#pragma unroll
        for (int j = 0; j < 4; j++) {
            const int nn = n0 + wn * 64 + j * 16 + l16;
            const float bv = bias[nn];
#pragma unroll
            for (int r = 0; r < 4; r++) {
                const int mm = m0 + wm * 64 + i * 16 + quad * 4 + r;
                float v = acc[i][j][r] + bv;
                if (do_gelu) v = 0.5f * v * (1.f + erff(v * 0.70710678118654752f));
                if (residual) v += residual[(size_t)mm * N + nn];
                if (out32) out32[(size_t)mm * N + nn] = v;
                if (out16) out16[(size_t)mm * N + nn] = f2b(v);
            }
        }
    }
}

// ---------------------------------------------------------------------------
// Barrier-free flash ALiBi attention (static-shift max-free softmax).
// True logit (exp2 dom): qk*qs2 + slope2*(q-k). Subtracting the static
// per-row shift slope2*q + 16 (>= true row max since qk*qs2 is small and
// the ALiBi ramp peaks at k=0) gives exponent = qk*qs2 - slope2*k - 16:
// q cancels entirely; shift cancels in normalization. No overflow
// (p <= 2^-12), no zero-l (p(k=0) >= 2^-40), distant-key underflow -> 0
// which equals the true softmax weight. No m-tracking/corr/rescale.
// All MFMA fragments load DIRECTLY from global (L2-resident qkv/vT).
// LDS: only Ps (9 KB). ZERO barriers. Triangle-paired q-tiles.
// ---------------------------------------------------------------------------
#define LOG2E 1.4426950408889634f

__global__ __launch_bounds__(256) void attn_mfma_kernel(
        const ushort* __restrict__ qkv,
        const ushort* __restrict__ vT,
        ushort* __restrict__ y, int B, int T) {
    const int C3 = 3 * N_EMBD;
    const int NT = T / 64;                  // 32
    const int p  = blockIdx.x;              // 0..15
    const int h  = blockIdx.y;
    const int b  = blockIdx.z;
    const int qtA = NT - 1 - p;
    const int qtB = p;
    const int tid  = threadIdx.x;
    const int lane = tid & 63;
    const int w    = tid >> 6;
    const int quad = lane >> 4;
    const int l16  = lane & 15;

    __shared__ ushort Ps[64][72];           // wave-private 16-row strips

    const float slope2 = exp2f(-0.5f * (float)(h + 1)) * LOG2E;
    const float qs2    = 0.125f * LOG2E;
    const float skb_l  = slope2 * (float)l16;   // per-lane k-bias

    const int q0A = qtA * 64, q0B = qtB * 64;
    const ushort* qh = qkv + (size_t)b * T * C3 + h * HEAD_D;
    const ushort* vh = vT + (size_t)(b * N_HEADC + h) * HEAD_D * T;

    // ---- Q fragments, direct from global ----
    const int mrow = w * 16 + l16;
    short8 aqA0 = *(const short8*)&qh[(size_t)(q0A + mrow) * C3 + quad * 8];
    short8 aqA1 = *(const short8*)&qh[(size_t)(q0A + mrow) * C3 + 32 + quad * 8];
    short8 aqB0 = *(const short8*)&qh[(size_t)(q0B + mrow) * C3 + quad * 8];
    short8 aqB1 = *(const short8*)&qh[(size_t)(q0B + mrow) * C3 + 32 + quad * 8];

    float lA[4] = {0.f, 0.f, 0.f, 0.f}, lB[4] = {0.f, 0.f, 0.f, 0.f};
    floatx4 accA[4], accB[4];
#pragma unroll
    for (int i = 0; i < 4; i++) {
        accA[i] = (floatx4){0.f, 0.f, 0.f, 0.f};
        accB[i] = (floatx4){0.f, 0.f, 0.f, 0.f};
    }

    for (int kt = 0; kt <= qtA; kt++) {
        const int k0 = kt * 64;
        // ---- K fragments (B-layout), direct global ----
        short8 bk[4][2];
#pragma unroll
        for (int kb = 0; kb < 4; kb++) {
            const size_t krow = (size_t)(k0 + kb * 16 + l16) * C3 + N_EMBD;
            bk[kb][0] = *(const short8*)&qh[krow + quad * 8];
            bk[kb][1] = *(const short8*)&qh[krow + 32 + quad * 8];
        }
        // ---- V fragments (B-layout), direct global from vT ----
        short8 bv[4][2];
#pragma unroll
        for (int db = 0; db < 4; db++) {
            const size_t vrow = (size_t)(db * 16 + l16) * T + k0;
            bv[db][0] = *(const short8*)&vh[vrow + quad * 8];
            bv[db][1] = *(const short8*)&vh[vrow + 32 + quad * 8];
        }

        // per-kb exponent constant: -slope2*(k0 + kb*16 + l16) - 16
        float ckb[4];
#pragma unroll
        for (int kb = 0; kb < 4; kb++)
            ckb[kb] = -slope2 * (float)(k0 + kb * 16) - skb_l - 16.0f;

        const bool lastB = (kt <= qtB);
#pragma unroll
        for (int tile = 0; tile < 2; tile++) {
            if (tile == 1 && !lastB) break;
            const int q0 = tile ? q0B : q0A;
            const bool diag = tile ? (kt == qtB) : (kt == qtA);
            const short8 aq0 = tile ? aqB0 : aqA0;
            const short8 aq1 = tile ? aqB1 : aqA1;
            float* l_r = tile ? lB : lA;
            floatx4* acc = tile ? accB : accA;

            // QK^T
            floatx4 sf[4];
#pragma unroll
            for (int kb = 0; kb < 4; kb++) {
                floatx4 s = (floatx4){0.f, 0.f, 0.f, 0.f};
                s = __builtin_amdgcn_mfma_f32_16x16x32_bf16(aq0, bk[kb][0], s, 0, 0, 0);
                s = __builtin_amdgcn_mfma_f32_16x16x32_bf16(aq1, bk[kb][1], s, 0, 0, 0);
                sf[kb] = s;
            }

            // static-shift max-free softmax: p = exp2(qk*qs2 - slope2*k - 16)
#pragma unroll
            for (int r = 0; r < 4; r++) {
                const int q = q0 + w * 16 + quad * 4 + r;
                float rs = 0.f;
                const int prow = w * 16 + quad * 4 + r;
#pragma unroll
                for (int kb = 0; kb < 4; kb++) {
                    float s2 = fmaf(sf[kb][r], qs2, ckb[kb]);
                    if (diag) {
                        const int k = k0 + kb * 16 + l16;
                        s2 = (k <= q) ? s2 : -INFINITY;
                    }
                    const float pv = exp2f(s2);
                    rs += pv;
                    Ps[prow][kb * 16 + l16] = f2b(pv);
                }
                l_r[r] += rowsum16(rs);
            }

            // PV (Ps strip wave-private; compiler inserts lgkmcnt)
            short8 ap0 = *(const short8*)&Ps[w * 16 + l16][quad * 8];
            short8 ap1 = *(const short8*)&Ps[w * 16 + l16][32 + quad * 8];
#pragma unroll
            for (int db = 0; db < 4; db++) {
                acc[db] = __builtin_amdgcn_mfma_f32_16x16x32_bf16(ap0, bv[db][0], acc[db], 0, 0, 0);
                acc[db] = __builtin_amdgcn_mfma_f32_16x16x32_bf16(ap1, bv[db][1], acc[db], 0, 0, 0);
            }
        }
    }

    // ---- epilogue ----
#pragma unroll
    for (int r = 0; r < 4; r++) {
        const int qa = q0A + w * 16 + quad * 4 + r;
        const int qb = q0B + w * 16 + quad * 4 + r;
        const float ia = 1.f / lA[r];
        const float ib = 1.f / lB[r];
#pragma unroll
        for (int db = 0; db < 4; db++) {
            y[((size_t)b * T + qa) * N_EMBD + h * HEAD_D + db * 16 + l16] =
                f2b(accA[db][r] * ia);
            y[((size_t)b * T + qb) * N_EMBD + h * HEAD_D + db * 16 + l16] =
                f2b(accB[db][r] * ib);
        }
    }
}

// ---------------------------------------------------------------------------
extern "C" void kernel_launch(void* const* d_in, const int* in_sizes, int n_in,
                              void* d_out, int out_size, void* d_ws, size_t ws_size,
                              hipStream_t stream) {
    const int B = 2, T = 2048, C = N_EMBD;
    const int M = B * T;
    const int NT = T / 64;

    const float* x      = (const float*)d_in[0];
    const float* ln1_w  = (const float*)d_in[1];
    const float* ln1_b  = (const float*)d_in[2];
    const float* w_qkv  = (const float*)d_in[3];
    const float* b_qkv  = (const float*)d_in[4];
    const float* w_proj = (const float*)d_in[5];
    const float* b_proj = (const float*)d_in[6];
    const float* ln2_w  = (const float*)d_in[7];
    const float* ln2_b  = (const float*)d_in[8];
    const float* w_fc   = (const float*)d_in[9];
    const float* b_fc   = (const float*)d_in[10];
    const float* w_fc2  = (const float*)d_in[11];
    const float* b_fc2  = (const float*)d_in[12];
    float* out = (float*)d_out;

    char* ws = (char*)d_ws;
    size_t off = 0;
    ushort* wt_qkv  = (ushort*)(ws + off); off += (size_t)3 * C * C * 2;
    ushort* wt_proj = (ushort*)(ws + off); off += (size_t)C * C * 2;
    ushort* wt_fc   = (ushort*)(ws + off); off += (size_t)4 * C * C * 2;
    ushort* wt_fc2  = (ushort*)(ws + off); off += (size_t)4 * C * C * 2;
    ushort* h16     = (ushort*)(ws + off); off += (size_t)M * C * 2;
    ushort* qkv16   = (ushort*)(ws + off); off += (size_t)M * 3 * C * 2;
    ushort* y16     = (ushort*)(ws + off); off += (size_t)M * C * 2;
    ushort* fc16    = (ushort*)(ws + off); off += (size_t)M * 4 * C * 2;
    ushort* vt16    = (ushort*)(ws + off); off += (size_t)M * C * 2;   // vT [B,H,64,T]

    // 0. weight transpose+convert
    convtrans_kernel<<<dim3(3 * C / 32, C / 32), 256, 0, stream>>>(w_qkv, wt_qkv, C, 3 * C);
    convtrans_kernel<<<dim3(C / 32, C / 32), 256, 0, stream>>>(w_proj, wt_proj, C, C);
    convtrans_kernel<<<dim3(4 * C / 32, C / 32), 256, 0, stream>>>(w_fc, wt_fc, C, 4 * C);
    convtrans_kernel<<<dim3(C / 32, 4 * C / 32), 256, 0, stream>>>(w_fc2, wt_fc2, 4 * C, C);

    // 1. h = LN1(x) -> bf16
    ln_kernel<<<M, 256, 0, stream>>>(x, ln1_w, ln1_b, h16, C);

    // 2. qkv = h @ w_qkv + b_qkv -> bf16
    gemm_bf16_kernel<<<dim3(3 * C / 128, M / 128), 256, 0, stream>>>(
        h16, wt_qkv, b_qkv, nullptr, nullptr, qkv16, M, 3 * C, C, 0);

    // 2b. vT = transpose(V part of qkv)
    vtrans_kernel<<<dim3(NT, N_HEADC, B), 256, 0, stream>>>(qkv16, vt16, B, T);

    // 3. barrier-free flash ALiBi attention -> bf16 y16
    attn_mfma_kernel<<<dim3(NT / 2, N_HEADC, B), 256, 0, stream>>>(
        qkv16, vt16, y16, B, T);

    // 4. x1 = x + y @ w_proj + b_proj -> d_out (fp32)
    gemm_bf16_kernel<<<dim3(C / 128, M / 128), 256, 0, stream>>>(
        y16, wt_proj, b_proj, x, out, nullptr, M, C, C, 0);

    // 5. h = LN2(x1) -> bf16
    ln_kernel<<<M, 256, 0, stream>>>(out, ln2_w, ln2_b, h16, C);

    // 6. fc = gelu(h @ w_fc + b_fc) -> bf16
    gemm_bf16_kernel<<<dim3(4 * C / 128, M / 128), 256, 0, stream>>>(
        h16, wt_fc, b_fc, nullptr, nullptr, fc16, M, 4 * C, C, 1);

    // 7. out = x1 + fc @ w_fc2 + b_fc2 -> d_out (fp32)
    gemm_bf16_kernel<<<dim3(C / 128, M / 128), 256, 0, stream>>>(
        fc16, wt_fc2, b_fc2, out, out, nullptr, M, C, 4 * C, 0);
}